// Round 3
// baseline (291.686 us; speedup 1.0000x reference)
//
#include <hip/hip_runtime.h>
#include <hip/hip_bf16.h>
#include <string.h>

#define GAMMA 0.015625f
#define D 64

typedef short bf16x8 __attribute__((ext_vector_type(8)));   // 8 bf16 = 4 VGPRs
typedef float floatx4 __attribute__((ext_vector_type(4)));

// ---------------------------------------------------------------------------
// Prep (fused for both inputs): fp32 [rows,64] -> bf16 [rows,64] + fp32 row
// norms of the ROUNDED values (so d2 = xsq + ysq - 2*cross is the exact
// squared distance of the bf16 vectors, >= 0 up to fp32 roundoff).
// One wave per row, lane k handles element k. 4 rows per block.
// ---------------------------------------------------------------------------
__global__ __launch_bounds__(256) void prep_kernel(const float* __restrict__ data,
                                                   const float* __restrict__ sv,
                                                   short* __restrict__ Abf,
                                                   short* __restrict__ Bbf,
                                                   float* __restrict__ xsq,
                                                   float* __restrict__ ysq,
                                                   int N, int total) {
    int wave = threadIdx.x >> 6;
    int lane = threadIdx.x & 63;
    int row  = blockIdx.x * 4 + wave;
    if (row >= total) return;

    const float* src;  short* dst;  float* nrm;  int r;
    if (row < N) { src = data; dst = Abf; nrm = xsq; r = row; }
    else         { src = sv;   dst = Bbf; nrm = ysq; r = row - N; }

    float v = src[(size_t)r * D + lane];
    __hip_bfloat16 b = __float2bfloat16(v);
    short bs;
    memcpy(&bs, &b, sizeof(short));
    dst[(size_t)r * D + lane] = bs;
    float bv = __bfloat162float(b);
    float sq = bv * bv;
#pragma unroll
    for (int off = 32; off > 0; off >>= 1) sq += __shfl_down(sq, off, 64);
    if (lane == 0) nrm[r] = sq;
}

// ---------------------------------------------------------------------------
// Fused RBF GEMM, operand-SWAPPED for a vectorized epilogue.
// MFMA A-operand = sv rows (m = sv index j), B-operand = data rows
// (n = data index i). D[m=j, n=i] layout: col(n=i) = lane&15,
// row(m=j) = quad*4 + reg  ->  each fragment's 4 regs are 4 consecutive
// OUTPUT COLUMNS of one output row  ->  one float4 store per fragment.
// Block tile: 128 data rows x 128 sv cols; 4 waves in 2x2, each 64x64.
// ---------------------------------------------------------------------------
__global__ __launch_bounds__(256) void rbf_gemm(const short* __restrict__ A,   // data bf16 [N,64]
                                                const short* __restrict__ B,   // sv   bf16 [M,64]
                                                const float* __restrict__ xsq, // data norms [N]
                                                const float* __restrict__ ysq, // sv norms   [M]
                                                float* __restrict__ out,
                                                int M) {
    const int wid  = threadIdx.x >> 6;
    const int lane = threadIdx.x & 63;
    const int quad = lane >> 4;
    const int l16  = lane & 15;

    const long i0 = (long)blockIdx.y * 128 + (wid >> 1) * 64;  // data rows
    const long j0 = (long)blockIdx.x * 128 + (wid & 1) * 64;   // sv cols

    bf16x8 svf[4][2], dat[4][2];
#pragma unroll
    for (int jb = 0; jb < 4; ++jb) {
        const bf16x8* p = (const bf16x8*)(B + (j0 + jb * 16 + l16) * D + quad * 8);
        svf[jb][0] = p[0];   // k = quad*8 + [0,8)
        svf[jb][1] = p[4];   // k = 32 + quad*8 + [0,8)
    }
#pragma unroll
    for (int ib = 0; ib < 4; ++ib) {
        const bf16x8* p = (const bf16x8*)(A + (i0 + ib * 16 + l16) * D + quad * 8);
        dat[ib][0] = p[0];
        dat[ib][1] = p[4];
    }

    floatx4 acc[4][4];   // [ib][jb]
#pragma unroll
    for (int ib = 0; ib < 4; ++ib)
#pragma unroll
        for (int jb = 0; jb < 4; ++jb)
            acc[ib][jb] = (floatx4){0.f, 0.f, 0.f, 0.f};

#pragma unroll
    for (int k = 0; k < 2; ++k)
#pragma unroll
        for (int ib = 0; ib < 4; ++ib)
#pragma unroll
            for (int jb = 0; jb < 4; ++jb)
                acc[ib][jb] = __builtin_amdgcn_mfma_f32_16x16x32_bf16(
                    svf[jb][k], dat[ib][k], acc[ib][jb], 0, 0, 0);

    // Epilogue: out[i][j] = exp(-gamma * max(xsq[i] + ysq[j] - 2*c, 0)).
    // Per fragment: one float4 nontemporal store at out[i][j0+jb*16+quad*4].
#pragma unroll
    for (int ib = 0; ib < 4; ++ib) {
        const long row = i0 + ib * 16 + l16;
        const float xn = xsq[row];
        float* orow = out + row * (long)M;
#pragma unroll
        for (int jb = 0; jb < 4; ++jb) {
            const long jcol = j0 + jb * 16 + quad * 4;
            const floatx4 yn = *(const floatx4*)(ysq + jcol);
            const floatx4 c = acc[ib][jb];
            floatx4 o;
            o[0] = __expf(-GAMMA * fmaxf(xn + yn[0] - 2.0f * c[0], 0.0f));
            o[1] = __expf(-GAMMA * fmaxf(xn + yn[1] - 2.0f * c[1], 0.0f));
            o[2] = __expf(-GAMMA * fmaxf(xn + yn[2] - 2.0f * c[2], 0.0f));
            o[3] = __expf(-GAMMA * fmaxf(xn + yn[3] - 2.0f * c[3], 0.0f));
            __builtin_nontemporal_store(o, (floatx4*)(orow + jcol));
        }
    }
}

// ---------------------------------------------------------------------------
// Fallback (only if ws_size is too small): direct fp32 distance.
// ---------------------------------------------------------------------------
__global__ __launch_bounds__(256) void rbf_naive(const float* __restrict__ X,
                                                 const float* __restrict__ Y,
                                                 float* __restrict__ out,
                                                 int N, int M) {
    long idx = (long)blockIdx.x * blockDim.x + threadIdx.x;
    if (idx >= (long)N * M) return;
    long i = idx / M, j = idx % M;
    float s = 0.0f;
#pragma unroll
    for (int k = 0; k < D; ++k) {
        float d = X[i * D + k] - Y[j * D + k];
        s = fmaf(d, d, s);
    }
    out[idx] = __expf(-GAMMA * s);
}

extern "C" void kernel_launch(void* const* d_in, const int* in_sizes, int n_in,
                              void* d_out, int out_size, void* d_ws, size_t ws_size,
                              hipStream_t stream) {
    const float* data = (const float*)d_in[0];
    const float* sv   = (const float*)d_in[1];
    float* out = (float*)d_out;
    const int N = in_sizes[0] / D;   // 8192
    const int M = in_sizes[1] / D;   // 8192

    const size_t bfA  = (size_t)N * D * sizeof(short);
    const size_t bfB  = (size_t)M * D * sizeof(short);
    const size_t need = bfA + bfB + (size_t)(N + M) * sizeof(float);

    if (ws_size >= need && (N % 128) == 0 && (M % 128) == 0) {
        char* ws = (char*)d_ws;
        short* Abf = (short*)ws;
        short* Bbf = (short*)(ws + bfA);
        float* xsq = (float*)(ws + bfA + bfB);
        float* ysq = xsq + N;

        const int total = N + M;
        hipLaunchKernelGGL(prep_kernel, dim3((total + 3) / 4), dim3(256), 0, stream,
                           data, sv, Abf, Bbf, xsq, ysq, N, total);
        dim3 grid(M / 128, N / 128);
        hipLaunchKernelGGL(rbf_gemm, grid, dim3(256), 0, stream,
                           Abf, Bbf, xsq, ysq, out, M);
    } else {
        long total = (long)N * M;
        long blocks = (total + 255) / 256;
        hipLaunchKernelGGL(rbf_naive, dim3((unsigned)blocks), dim3(256), 0, stream,
                           data, sv, out, N, M);
    }
}